// Round 17
// baseline (294.970 us; speedup 1.0000x reference)
//
#include <hip/hip_runtime.h>

// Problem constants
#define B_Q   4096
#define E_DIM 512
#define N_C   2000
#define N_P   64000

// Round 16: remove the LDS bottleneck.  r13/r15 accounting: per CU the LDS
// unit carries 192k cyc of frag reads + 64k cyc of staging writes (=107us)
// vs 163k cyc MFMA (68us) -- LDS-pipe-bound, which is why occupancy (r13),
// read balancing (r10) and SGB interleave (r15) were all null.  Fix: B (dq,
// 2 MB, L2-resident, reused 500x) bypasses LDS entirely -- fragments load
// DIRECTLY global->VGPR (per-lane addressing gives the exact MFMA layout;
// values byte-identical to the old swizzled-LDS path).  LDS holds A only:
// 96k+32k = 128k cyc (53us) < MFMA 68us -> MFMA becomes the binding pipe.
#define BM 128
#define BN 128

typedef int i32x4 __attribute__((ext_vector_type(4)));

__device__ __forceinline__ void async_ld16(const void* g, void* l) {
  __builtin_amdgcn_global_load_lds(
      (const __attribute__((address_space(1))) void*)g,
      (__attribute__((address_space(3))) void*)l,
      16, 0, 0);
}

// ---------------------------------------------------------------------------
// Row L2-normalize + per-row-scaled int8 quantization, both inputs (r12).
// ---------------------------------------------------------------------------
__global__ __launch_bounds__(128) void normq_kernel(
    const float* __restrict__ w1, const float* __restrict__ data,
    signed char* __restrict__ wq, signed char* __restrict__ dq,
    float* __restrict__ wsc, float* __restrict__ dsc)
{
  int row = blockIdx.x;
  const float* in; signed char* outq; float* sc;
  if (row < N_P) { in = w1;   outq = wq; sc = wsc; }
  else           { in = data; outq = dq; sc = dsc; row -= N_P; }
  const int tid = threadIdx.x;
  const float4 v = *(const float4*)(in + (size_t)row * E_DIM + tid * 4);
  float ss = v.x*v.x + v.y*v.y + v.z*v.z + v.w*v.w;
  float am = fmaxf(fmaxf(fabsf(v.x), fabsf(v.y)), fmaxf(fabsf(v.z), fabsf(v.w)));
  #pragma unroll
  for (int s = 1; s < 64; s <<= 1) {
    ss += __shfl_xor(ss, s);
    am = fmaxf(am, __shfl_xor(am, s));
  }
  __shared__ float pss[2], pam[2];
  if ((tid & 63) == 0) { pss[tid >> 6] = ss; pam[tid >> 6] = am; }
  __syncthreads();
  const float inv = 1.0f / fmaxf(sqrtf(pss[0] + pss[1]), 1e-12f);
  const float m   = fmaxf(fmaxf(pam[0], pam[1]) * inv, 1e-20f);
  const float qs  = 127.0f / m * inv;          // v * qs in [-127, 127]
  char4 o;
  o.x = (signed char)__float2int_rn(v.x * qs);
  o.y = (signed char)__float2int_rn(v.y * qs);
  o.z = (signed char)__float2int_rn(v.z * qs);
  o.w = (signed char)__float2int_rn(v.w * qs);
  *(char4*)(outq + (size_t)row * E_DIM + tid * 4) = o;
  if (tid == 0) sc[row] = m * (1.0f / 127.0f);
}

// ---------------------------------------------------------------------------
// LDS (16384 B): A[buf][128 rows][4 x 16B], buf stride 8192.  k-tile = BK=64
// i8 = 64 B/row; 8 tiles double-buffered (tile t in buf t&1).  Chunk swizzle
// (verified): slot (row,cc) holds global chunk cc ^ ((row>>1)&3); stager
// pre-swizzles the GLOBAL chunk, LDS dest linear.
// B fragments: DIRECT global loads, no LDS.  Lane l, tile n, k-tile kt reads
// 16 B at dq[(colBase + wc*64 + n*16 + (l&15))*512 + kt*64 + (l>>4)*16] --
// exactly the bytes the old LDS path delivered (slot kg^f of a tile whose
// slot cc holds chunk cc^f  ==  global chunk kg).
//
// vmcnt ledger (per-iter issues: A-stage 2 ops, B-load 4 ops):
//   prologue: A(0)2 A(1)2 B(0)4; WAITV(4) retires A(0),A(1); RD_A tile0;
//             LGKM0 (r14 race fix: reads drain before buf0 restage)
//   iter t:   SBAR1 (tile-t reads block-wide drained -> restage safe);
//             STAGE_A(t+2) 2; LOADB(t+1)->set (t+1)&1, 4;
//             WAITV(6) retires exactly {A(t+1) [tail legality], B(t) [MFMA]};
//             SBAR2 (A(t+1) visible block-wide);
//             16 MFMA (A=fa[t&1] from LDS, B=gb[t&1] regs) interleaved with
//             4 tail ds_reads of A(t+1) -> fa[(t+1)&1]; LGKM0.
//   t=6: no A-stage, WAITV(4); t=7: nothing, WAITV(0).
// ---------------------------------------------------------------------------
#define WAITV(N) asm volatile("s_waitcnt vmcnt(" #N ")" ::: "memory")
#define LGKM0    asm volatile("s_waitcnt lgkmcnt(0)" ::: "memory")
#define SBAR     asm volatile("s_barrier" ::: "memory")
#define NOPS     do {} while (0)

#define STAGE_A(BUF,KOFF) do { \
  async_ld16(gA + (KOFF)*64,         smem + (BUF)*8192 + sdst); \
  async_ld16(gA + 32768 + (KOFF)*64, smem + (BUF)*8192 + sdst + 4096); \
} while(0)

// B fragments for k-tile KT into register set S (4 global_load_dwordx4).
#define LOADB(S,KT) do { \
  gb##S##0 = *(const i32x4*)(gB0 + (KT)*64); \
  gb##S##1 = *(const i32x4*)(gB1 + (KT)*64); \
  gb##S##2 = *(const i32x4*)(gB2 + (KT)*64); \
  gb##S##3 = *(const i32x4*)(gB3 + (KT)*64); \
} while(0)

// A fragments of buffer BUF into register set S (4 ds_read_b128).
#define RD_A(S,BUF) do { \
  fa##S##0 = *(const i32x4*)(pa + (BUF)*8192 +    0); \
  fa##S##1 = *(const i32x4*)(pa + (BUF)*8192 + 1024); \
  fa##S##2 = *(const i32x4*)(pa + (BUF)*8192 + 2048); \
  fa##S##3 = *(const i32x4*)(pa + (BUF)*8192 + 3072); \
} while(0)

#define MM(S,m,n) \
  acc[m][n] = __builtin_amdgcn_mfma_i32_16x16x64_i8(fa##S##m, gb##S##n, acc[m][n], 0, 0, 0)

#define MFMA16(S) do { \
  MM(S,0,0); MM(S,0,1); MM(S,0,2); MM(S,0,3); \
  MM(S,1,0); MM(S,1,1); MM(S,1,2); MM(S,1,3); \
  MM(S,2,0); MM(S,2,1); MM(S,2,2); MM(S,2,3); \
  MM(S,3,0); MM(S,3,1); MM(S,3,2); MM(S,3,3); \
} while(0)

// Interleave 4 tail ds_reads among the 16 MFMA: {MFMA x2, DS x1} x4 + MFMA x8.
#define SGB(M,N) __builtin_amdgcn_sched_group_barrier(M, N, 0)
#define ILV4 do { \
  SGB(0x8,2); SGB(0x100,1); SGB(0x8,2); SGB(0x100,1); \
  SGB(0x8,2); SGB(0x100,1); SGB(0x8,2); SGB(0x100,1); \
  SGB(0x8,8); \
} while(0)

#define ITER(S, STAGEA, LDB, WAIT, TAIL, ILV) do { \
  SBAR; \
  STAGEA; \
  LDB; \
  WAIT; \
  SBAR; \
  __builtin_amdgcn_sched_barrier(0); \
  __builtin_amdgcn_s_setprio(1); \
  MFMA16(S); \
  TAIL; \
  ILV; \
  LGKM0; \
  __builtin_amdgcn_s_setprio(0); \
} while(0)

__global__ __launch_bounds__(256, 3) void gemm_max_kernel(
    const signed char* __restrict__ wq,   // [64000][512] i8, row-scaled
    const signed char* __restrict__ dq,   // [4096][512]  i8, row-scaled
    const float* __restrict__ wsc,        // [64000] dequant scales
    const float* __restrict__ dsc,        // [4096]  dequant scales
    float* __restrict__ out)              // [2000][4096]
{
  __shared__ __align__(16) char smem[16384];

  const int tid  = threadIdx.x;
  const int lane = tid & 63;
  const int wid  = tid >> 6;      // 0..3
  const int wr   = wid >> 1;      // 0..1  (64 rows each)
  const int wc   = wid & 1;       // 0..1  (64 cols each)

  // XCD-aware bijective chunked swizzle: 16000 blocks, 2000/XCD.
  const int bid  = blockIdx.x;
  const int wgid = (bid & 7) * 2000 + (bid >> 3);
  const int rowb = wgid >> 5;     // 0..499
  const int colb = wgid & 31;     // 0..31
  const int rowBase = rowb * BM;
  const int colBase = colb * BN;

  // A staging: region = 128 rows x 64 B = 512 chunks of 16 B; thread t
  // handles chunks t (rows 0-63) and t+256 (rows 64-127).
  const int srow = tid >> 2;
  const int gch  = (tid & 3) ^ ((tid >> 3) & 3);
  const signed char* gA = wq + (size_t)(rowBase + srow) * E_DIM + gch * 16;
  const int sdst = tid * 16;      // linear LDS dest

  // A fragment read base (swizzled chunk).
  const int r   = lane & 15;
  const int kg  = lane >> 4;
  const int swz = (kg ^ ((r >> 1) & 3)) * 16;
  const char* pa = smem + (wr * 64 + r) * 64 + swz;

  // B fragment global bases: lane reads col (wc*64 + n*16 + r), bytes
  // kt*64 + kg*16 .. +16 of that row.
  const signed char* gBb = dq + (size_t)(colBase + wc * 64 + r) * E_DIM + kg * 16;
  const signed char* gB0 = gBb;
  const signed char* gB1 = gBb + 16 * E_DIM;
  const signed char* gB2 = gBb + 32 * E_DIM;
  const signed char* gB3 = gBb + 48 * E_DIM;

  i32x4 acc[4][4];
  #pragma unroll
  for (int m = 0; m < 4; ++m)
    #pragma unroll
    for (int n = 0; n < 4; ++n)
      acc[m][n] = (i32x4){0, 0, 0, 0};

  i32x4 fa00, fa01, fa02, fa03, fa10, fa11, fa12, fa13;   // A sets
  i32x4 gb00, gb01, gb02, gb03, gb10, gb11, gb12, gb13;   // B sets

  // Prologue: A tiles 0,1 -> buf0,buf1 (4 vm); B tile 0 -> set0 (4 vm);
  // WAITV(4) retires both A tiles; read tile-0 A frags; drain (race fix).
  STAGE_A(0,0);
  STAGE_A(1,1);
  LOADB(0,0);
  WAITV(4);
  SBAR;
  RD_A(0,0);
  LGKM0;

  // Iters t=0..7 (set/buf = t&1): stage A(t+2) for t<6, load B(t+1) for t<7.
  ITER(0, STAGE_A(0,2), LOADB(1,1), WAITV(6), RD_A(1,1), ILV4);
  ITER(1, STAGE_A(1,3), LOADB(0,2), WAITV(6), RD_A(0,0), ILV4);
  ITER(0, STAGE_A(0,4), LOADB(1,3), WAITV(6), RD_A(1,1), ILV4);
  ITER(1, STAGE_A(1,5), LOADB(0,4), WAITV(6), RD_A(0,0), ILV4);
  ITER(0, STAGE_A(0,6), LOADB(1,5), WAITV(6), RD_A(1,1), ILV4);
  ITER(1, STAGE_A(1,7), LOADB(0,6), WAITV(6), RD_A(0,0), ILV4);
  ITER(0, NOPS,         LOADB(1,7), WAITV(4), RD_A(1,1), ILV4);
  ITER(1, NOPS,         NOPS,       WAITV(0), NOPS,      NOPS);

  // Epilogue: dequant + per-class max.  Wave row = wr*64 + m*16 + kg*4 + j;
  // class = m-pair (32 rows).  Row scales BEFORE max, col scale after.
  float wsv[4][4];
  {
    #pragma unroll
    for (int m = 0; m < 4; ++m) {
      const float4 w4 = *(const float4*)(wsc + rowBase + wr * 64 + m * 16 + kg * 4);
      wsv[m][0] = w4.x; wsv[m][1] = w4.y; wsv[m][2] = w4.z; wsv[m][3] = w4.w;
    }
  }
  float dv[4];
  {
    const float* dscp = dsc + colBase + wc * 64 + r;
    #pragma unroll
    for (int n = 0; n < 4; ++n) dv[n] = dscp[n * 16];
  }
  const int classBase = rowb * 4 + wr * 2;
  #pragma unroll
  for (int q = 0; q < 2; ++q) {
    #pragma unroll
    for (int n = 0; n < 4; ++n) {
      float pm = -3.4e38f;
      #pragma unroll
      for (int j = 0; j < 4; ++j)
        pm = fmaxf(pm, fmaxf((float)acc[2*q][n][j]   * wsv[2*q][j],
                             (float)acc[2*q+1][n][j] * wsv[2*q+1][j]));
      pm = fmaxf(pm, __shfl_xor(pm, 16));
      pm = fmaxf(pm, __shfl_xor(pm, 32));
      if (lane < 16)
        out[(size_t)(classBase + q) * B_Q + colBase + wc * 64 + n * 16 + r]
            = pm * dv[n];
    }
  }
}

// ---------------------------------------------------------------------------
extern "C" void kernel_launch(void* const* d_in, const int* in_sizes, int n_in,
                              void* d_out, int out_size, void* d_ws, size_t ws_size,
                              hipStream_t stream) {
  const float* data = (const float*)d_in[0];   // [4096][512]
  const float* w1   = (const float*)d_in[1];   // [64000][512]
  float* out = (float*)d_out;                  // [2000][4096]

  signed char* wq = (signed char*)d_ws;                       // 32.77 MB
  signed char* dq = wq + (size_t)N_P * E_DIM;                 //  2.10 MB
  float* wsc = (float*)(dq + (size_t)B_Q * E_DIM);            // 256 KB
  float* dsc = wsc + N_P;                                     //  16 KB

  normq_kernel<<<N_P + B_Q, 128, 0, stream>>>(w1, data, wq, dq, wsc, dsc);
  gemm_max_kernel<<<(N_P / BM) * (B_Q / BN), 256, 0, stream>>>(wq, dq, wsc, dsc, out);
}

// Round 18
// 181.318 us; speedup vs baseline: 1.6268x; 1.6268x over previous
//
#include <hip/hip_runtime.h>

// Problem constants
#define B_Q   4096
#define E_DIM 512
#define N_C   2000
#define N_P   64000

// Round 17: r16 (B bypasses LDS; LDS carries A only) with B loads made
// FULLY COALESCED.  r16's collapse (293us, MfmaUtil 19%) was the B access
// pattern: each load had 16 lanes reading 16 different 512B-strided rows ->
// 16 scattered 64B transactions/instr, flooding L2 queues.  Fix: normq
// writes the d-side in FRAGMENT-PACKED layout -- dqf[(c16*8+kt)*1024 +
// lane*16] holds exactly lane `lane`'s 16B fragment for 16-col tile c16,
// k-tile kt (bytes identical to the old swizzled-LDS path).  LOADB is then
// one contiguous 1KB wave transaction from L2-resident (2MB) data.
// Ledger, A path, tail reads, ILV: r16 verbatim (absmax 2.93e-3 verified).
#define BM 128
#define BN 128

typedef int i32x4 __attribute__((ext_vector_type(4)));

__device__ __forceinline__ void async_ld16(const void* g, void* l) {
  __builtin_amdgcn_global_load_lds(
      (const __attribute__((address_space(1))) void*)g,
      (__attribute__((address_space(3))) void*)l,
      16, 0, 0);
}

// ---------------------------------------------------------------------------
// Row L2-normalize + per-row-scaled int8 quantization.
// w-rows -> linear layout wq[row][512] (feeds the LDS staging path).
// d-rows -> FRAGMENT-PACKED dqf: for row (col) c = c16*16 + r, element
// k = kt*64 + kg*16 + b (b<16):  dqf[(c16*8 + kt)*1024 + (kg*16 + r)*16 + b].
// A wave's B-fragment load for (c16, kt) is then dqf[(c16*8+kt)*1024 + lane*16],
// lane = kg*16 + r -- one contiguous 1KB transaction.
// ---------------------------------------------------------------------------
__global__ __launch_bounds__(128) void normq_kernel(
    const float* __restrict__ w1, const float* __restrict__ data,
    signed char* __restrict__ wq, signed char* __restrict__ dqf,
    float* __restrict__ wsc, float* __restrict__ dsc)
{
  int row = blockIdx.x;
  const bool isW = (row < N_P);
  const float* in;
  if (isW) { in = w1; }
  else     { in = data; row -= N_P; }
  const int tid = threadIdx.x;
  const float4 v = *(const float4*)(in + (size_t)row * E_DIM + tid * 4);
  float ss = v.x*v.x + v.y*v.y + v.z*v.z + v.w*v.w;
  float am = fmaxf(fmaxf(fabsf(v.x), fabsf(v.y)), fmaxf(fabsf(v.z), fabsf(v.w)));
  #pragma unroll
  for (int s = 1; s < 64; s <<= 1) {
    ss += __shfl_xor(ss, s);
    am = fmaxf(am, __shfl_xor(am, s));
  }
  __shared__ float pss[2], pam[2];
  if ((tid & 63) == 0) { pss[tid >> 6] = ss; pam[tid >> 6] = am; }
  __syncthreads();
  const float inv = 1.0f / fmaxf(sqrtf(pss[0] + pss[1]), 1e-12f);
  const float m   = fmaxf(fmaxf(pam[0], pam[1]) * inv, 1e-20f);
  const float qs  = 127.0f / m * inv;          // v * qs in [-127, 127]
  char4 o;
  o.x = (signed char)__float2int_rn(v.x * qs);
  o.y = (signed char)__float2int_rn(v.y * qs);
  o.z = (signed char)__float2int_rn(v.z * qs);
  o.w = (signed char)__float2int_rn(v.w * qs);
  if (isW) {
    *(char4*)(wq + (size_t)row * E_DIM + tid * 4) = o;
    if (tid == 0) wsc[row] = m * (1.0f / 127.0f);
  } else {
    // k = tid*4: kt = tid>>4, kg = (tid>>2)&3, byte-in-chunk = (tid&3)*4
    const int c16 = row >> 4, r = row & 15;
    const int kt = tid >> 4, kg = (tid >> 2) & 3;
    *(char4*)(dqf + (size_t)(c16 * 8 + kt) * 1024 + (kg * 16 + r) * 16
                  + (tid & 3) * 4) = o;
    if (tid == 0) dsc[row] = m * (1.0f / 127.0f);
  }
}

// ---------------------------------------------------------------------------
// LDS (16384 B): A[buf][128 rows][4 x 16B], buf stride 8192.  k-tile = BK=64
// i8 = 64 B/row; 8 tiles double-buffered (tile t in buf t&1).  Chunk swizzle
// (verified): slot (row,cc) holds global chunk cc ^ ((row>>1)&3).
// B fragments: direct coalesced global loads from dqf (no LDS).
//
// vmcnt ledger (per-iter issues: A-stage 2 ops, B-load 4 ops) [r16-verified]:
//   prologue: A(0)2 A(1)2 B(0)4; WAITV(4) retires A(0),A(1); RD_A tile0;
//             LGKM0 (race fix: reads drain before buf0 restage)
//   iter t:   SBAR1; STAGE_A(t+2)2; LOADB(t+1)4;
//             WAITV(6) retires exactly {A(t+1), B(t)};
//             SBAR2; 16 MFMA + 4 tail ds_reads of A(t+1) via SGB; LGKM0.
//   t=6: no A-stage, WAITV(4); t=7: nothing, WAITV(0).
// ---------------------------------------------------------------------------
#define WAITV(N) asm volatile("s_waitcnt vmcnt(" #N ")" ::: "memory")
#define LGKM0    asm volatile("s_waitcnt lgkmcnt(0)" ::: "memory")
#define SBAR     asm volatile("s_barrier" ::: "memory")
#define NOPS     do {} while (0)

#define STAGE_A(BUF,KOFF) do { \
  async_ld16(gA + (KOFF)*64,         smem + (BUF)*8192 + sdst); \
  async_ld16(gA + 32768 + (KOFF)*64, smem + (BUF)*8192 + sdst + 4096); \
} while(0)

// B fragments for k-tile KT into set S: 4 coalesced 1KB wave transactions.
#define LOADB(S,KT) do { \
  gb##S##0 = *(const i32x4*)(gBp + ((0*8 + (KT)) * 1024)); \
  gb##S##1 = *(const i32x4*)(gBp + ((1*8 + (KT)) * 1024)); \
  gb##S##2 = *(const i32x4*)(gBp + ((2*8 + (KT)) * 1024)); \
  gb##S##3 = *(const i32x4*)(gBp + ((3*8 + (KT)) * 1024)); \
} while(0)

// A fragments of buffer BUF into register set S (4 ds_read_b128).
#define RD_A(S,BUF) do { \
  fa##S##0 = *(const i32x4*)(pa + (BUF)*8192 +    0); \
  fa##S##1 = *(const i32x4*)(pa + (BUF)*8192 + 1024); \
  fa##S##2 = *(const i32x4*)(pa + (BUF)*8192 + 2048); \
  fa##S##3 = *(const i32x4*)(pa + (BUF)*8192 + 3072); \
} while(0)

#define MM(S,m,n) \
  acc[m][n] = __builtin_amdgcn_mfma_i32_16x16x64_i8(fa##S##m, gb##S##n, acc[m][n], 0, 0, 0)

#define MFMA16(S) do { \
  MM(S,0,0); MM(S,0,1); MM(S,0,2); MM(S,0,3); \
  MM(S,1,0); MM(S,1,1); MM(S,1,2); MM(S,1,3); \
  MM(S,2,0); MM(S,2,1); MM(S,2,2); MM(S,2,3); \
  MM(S,3,0); MM(S,3,1); MM(S,3,2); MM(S,3,3); \
} while(0)

// Interleave 4 tail ds_reads among the 16 MFMA: {MFMA x2, DS x1} x4 + MFMA x8.
#define SGB(M,N) __builtin_amdgcn_sched_group_barrier(M, N, 0)
#define ILV4 do { \
  SGB(0x8,2); SGB(0x100,1); SGB(0x8,2); SGB(0x100,1); \
  SGB(0x8,2); SGB(0x100,1); SGB(0x8,2); SGB(0x100,1); \
  SGB(0x8,8); \
} while(0)

#define ITER(S, STAGEA, LDB, WAIT, TAIL, ILV) do { \
  SBAR; \
  STAGEA; \
  LDB; \
  WAIT; \
  SBAR; \
  __builtin_amdgcn_sched_barrier(0); \
  __builtin_amdgcn_s_setprio(1); \
  MFMA16(S); \
  TAIL; \
  ILV; \
  LGKM0; \
  __builtin_amdgcn_s_setprio(0); \
} while(0)

__global__ __launch_bounds__(256, 3) void gemm_max_kernel(
    const signed char* __restrict__ wq,   // [64000][512] i8, linear
    const signed char* __restrict__ dqf,  // [256][8][1024] fragment-packed
    const float* __restrict__ wsc,        // [64000] dequant scales
    const float* __restrict__ dsc,        // [4096]  dequant scales
    float* __restrict__ out)              // [2000][4096]
{
  __shared__ __align__(16) char smem[16384];

  const int tid  = threadIdx.x;
  const int lane = tid & 63;
  const int wid  = tid >> 6;      // 0..3
  const int wr   = wid >> 1;      // 0..1  (64 rows each)
  const int wc   = wid & 1;       // 0..1  (64 cols each)

  // XCD-aware bijective chunked swizzle: 16000 blocks, 2000/XCD.
  const int bid  = blockIdx.x;
  const int wgid = (bid & 7) * 2000 + (bid >> 3);
  const int rowb = wgid >> 5;     // 0..499
  const int colb = wgid & 31;     // 0..31
  const int rowBase = rowb * BM;
  const int colBase = colb * BN;

  // A staging: region = 128 rows x 64 B = 512 chunks of 16 B.
  const int srow = tid >> 2;
  const int gch  = (tid & 3) ^ ((tid >> 3) & 3);
  const signed char* gA = wq + (size_t)(rowBase + srow) * E_DIM + gch * 16;
  const int sdst = tid * 16;      // linear LDS dest

  // A fragment read base (swizzled chunk).
  const int r   = lane & 15;
  const int kg  = lane >> 4;
  const int swz = (kg ^ ((r >> 1) & 3)) * 16;
  const char* pa = smem + (wr * 64 + r) * 64 + swz;

  // B fragment base: 16-col tile index c16 = colb*8 + wc*4 + n; fragment
  // block (c16*8 + kt)*1024; lane offset lane*16.  n-stride = 8*1024.
  const signed char* gBp = dqf + (size_t)(colb * 8 + wc * 4) * 8 * 1024
                               + lane * 16;

  i32x4 acc[4][4];
  #pragma unroll
  for (int m = 0; m < 4; ++m)
    #pragma unroll
    for (int n = 0; n < 4; ++n)
      acc[m][n] = (i32x4){0, 0, 0, 0};

  i32x4 fa00, fa01, fa02, fa03, fa10, fa11, fa12, fa13;   // A sets
  i32x4 gb00, gb01, gb02, gb03, gb10, gb11, gb12, gb13;   // B sets

  // Prologue: A tiles 0,1 -> buf0,buf1 (4 vm); B tile 0 -> set0 (4 vm);
  // WAITV(4) retires both A tiles; read tile-0 A frags; drain (race fix).
  STAGE_A(0,0);
  STAGE_A(1,1);
  LOADB(0,0);
  WAITV(4);
  SBAR;
  RD_A(0,0);
  LGKM0;

  // Iters t=0..7 (set/buf = t&1): stage A(t+2) for t<6, load B(t+1) for t<7.
  ITER(0, STAGE_A(0,2), LOADB(1,1), WAITV(6), RD_A(1,1), ILV4);
  ITER(1, STAGE_A(1,3), LOADB(0,2), WAITV(6), RD_A(0,0), ILV4);
  ITER(0, STAGE_A(0,4), LOADB(1,3), WAITV(6), RD_A(1,1), ILV4);
  ITER(1, STAGE_A(1,5), LOADB(0,4), WAITV(6), RD_A(0,0), ILV4);
  ITER(0, STAGE_A(0,6), LOADB(1,5), WAITV(6), RD_A(1,1), ILV4);
  ITER(1, STAGE_A(1,7), LOADB(0,6), WAITV(6), RD_A(0,0), ILV4);
  ITER(0, NOPS,         LOADB(1,7), WAITV(4), RD_A(1,1), ILV4);
  ITER(1, NOPS,         NOPS,       WAITV(0), NOPS,      NOPS);

  // Epilogue: dequant + per-class max.  Wave row = wr*64 + m*16 + kg*4 + j;
  // class = m-pair (32 rows).  Row scales BEFORE max, col scale after.
  float wsv[4][4];
  {
    #pragma unroll
    for (int m = 0; m < 4; ++m) {
      const float4 w4 = *(const float4*)(wsc + rowBase + wr * 64 + m * 16 + kg * 4);
      wsv[m][0] = w4.x; wsv[m][1] = w4.y; wsv[m][2] = w4.z; wsv[m][3] = w4.w;
    }
  }
  float dv[4];
  {
    const float* dscp = dsc + colBase + wc * 64 + r;
    #pragma unroll
    for (int n = 0; n < 4; ++n) dv[n] = dscp[n * 16];
  }
  const int classBase = rowb * 4 + wr * 2;
  #pragma unroll
  for (int q = 0; q < 2; ++q) {
    #pragma unroll
    for (int n = 0; n < 4; ++n) {
      float pm = -3.4e38f;
      #pragma unroll
      for (int j = 0; j < 4; ++j)
        pm = fmaxf(pm, fmaxf((float)acc[2*q][n][j]   * wsv[2*q][j],
                             (float)acc[2*q+1][n][j] * wsv[2*q+1][j]));
      pm = fmaxf(pm, __shfl_xor(pm, 16));
      pm = fmaxf(pm, __shfl_xor(pm, 32));
      if (lane < 16)
        out[(size_t)(classBase + q) * B_Q + colBase + wc * 64 + n * 16 + r]
            = pm * dv[n];
    }
  }
}

// ---------------------------------------------------------------------------
extern "C" void kernel_launch(void* const* d_in, const int* in_sizes, int n_in,
                              void* d_out, int out_size, void* d_ws, size_t ws_size,
                              hipStream_t stream) {
  const float* data = (const float*)d_in[0];   // [4096][512]
  const float* w1   = (const float*)d_in[1];   // [64000][512]
  float* out = (float*)d_out;                  // [2000][4096]

  signed char* wq  = (signed char*)d_ws;                      // 32.77 MB
  signed char* dqf = wq + (size_t)N_P * E_DIM;                //  2.10 MB
  float* wsc = (float*)(dqf + (size_t)B_Q * E_DIM);           // 256 KB
  float* dsc = wsc + N_P;                                     //  16 KB

  normq_kernel<<<N_P + B_Q, 128, 0, stream>>>(w1, data, wq, dqf, wsc, dsc);
  gemm_max_kernel<<<(N_P / BM) * (B_Q / BN), 256, 0, stream>>>(wq, dqf, wsc, dsc, out);
}